// Round 7
// baseline (183.870 us; speedup 1.0000x reference)
//
#include <hip/hip_runtime.h>
#include <stdint.h>

// CRF forward loss, chunked parallel scan in linear space — single fused kernel.
// One wave per 16-step chunk (nch = 32*B waves). M <- E_s * M, s descending.
// A = E_s rows, B = M via transposed image TM; dense 128B LDS rows with
// XOR-16B swizzle (phys = logical ^ ((row&7)<<4)) -> all b128 reads <=2-way.
// No register tile prefetch (round-4/6 regression: VGPR pressure), no forced
// occupancy bound. f32->bf16 packing via v_cvt_pk_bf16_f32 (RNE, = old f2bf).
// Combine fused: per-batch agent-scope ACQ_REL counter; 32nd chunk-wave of a
// batch runs the serial alpha matvec over the 32 released chunk matrices.

#define T_LEN 512
#define KK 48
#define NSTART 46
#define NEND 47
#define RPITCH 128                 // dense row: 64 bf16 (48 real + 16 zero K-pad)
#define REGION (48 * RPITCH)       // 6144 B
#define WAVE_LDS (2 * REGION)      // 12288 B per wave (E + TM)
#define CHB 4608                   // 48x48 bf16 chunk matrix (transposed, pitch 96)

typedef __attribute__((ext_vector_type(8))) short short8;
typedef __attribute__((ext_vector_type(4))) float f32x4;

__device__ __forceinline__ uint32_t cvt_pk_bf16(float lo, float hi) {
  uint32_t r;
  asm("v_cvt_pk_bf16_f32 %0, %1, %2" : "=v"(r) : "v"(lo), "v"(hi));
  return r;  // lo in bits 0..15, hi in bits 16..31 (RNE)
}
__device__ __forceinline__ float bf2f(uint32_t h) { return __uint_as_float(h << 16); }

// decode mask encoding (u8 bool / f32 / i32 / i64), popcount row b (prefix mask)
__device__ __forceinline__ int mask_len(const void* mask, int b, int lane) {
  const uint32_t w0 = ((const uint32_t*)mask)[0];
  const uint32_t w1 = ((const uint32_t*)mask)[1];
  int c = 0;
  if (w0 == 0x01010101u) {
    const unsigned long long* m8 =
        (const unsigned long long*)((const unsigned char*)mask + (size_t)b * T_LEN);
    c = (int)__popcll(m8[lane]);
  } else if (w0 == 0x3F800000u) {
    const float* mf = (const float*)mask + (size_t)b * T_LEN;
#pragma unroll
    for (int j = 0; j < 8; ++j) c += (mf[lane + 64 * j] != 0.0f);
  } else if (w1 == 1u) {
    const uint32_t* mi = (const uint32_t*)mask + (size_t)b * T_LEN;
#pragma unroll
    for (int j = 0; j < 8; ++j) c += (mi[lane + 64 * j] != 0u);
  } else {
    const unsigned long long* ml =
        (const unsigned long long*)mask + (size_t)b * T_LEN;
#pragma unroll
    for (int j = 0; j < 8; ++j) c += (ml[lane + 64 * j] != 0ull);
  }
#pragma unroll
  for (int d = 1; d < 64; d <<= 1) c += __shfl_xor(c, d);
  return c > T_LEN ? T_LEN : (c < 0 ? 0 : c);
}

__global__ __launch_bounds__(256) void k2_fused(
    const float* __restrict__ scores, const int* __restrict__ targets,
    const void* __restrict__ mask, unsigned char* __restrict__ wsT,
    int* __restrict__ wsExpo, float* __restrict__ wsGold,
    int* __restrict__ wsCnt, float* __restrict__ out, int nch, int B) {
  __shared__ __align__(16) unsigned char smem[4][WAVE_LDS];
  const int wid = threadIdx.x >> 6, lane = threadIdx.x & 63;
  const int g = blockIdx.x * 4 + wid;
  if (g >= nch) return;
  const int cix = g / B;  // balanced: consecutive g -> same cix, diff b
  const int b = g - cix * B;
  const int len = mask_len(mask, b, lane);
  int steps = len - (cix << 4);
  if (steps > 16) steps = 16;

  const int c15 = lane & 15, h = lane >> 4;

  if (steps > 0) {
    unsigned char* E = smem[wid];    // E_s row-major; K-pad slots stay 0
    unsigned char* TM = E + REGION;  // M transposed; K-pad likewise

    {  // zero both regions: 768 x 16B
      int4* z = (int4*)E;
#pragma unroll
      for (int q = 0; q < 12; ++q) z[q * 64 + lane] = make_int4(0, 0, 0, 0);
    }
    // M := I (swizzled address: full logical offset XOR row-swizzle)
    if (lane < KK)
      *(ushort*)(TM + lane * RPITCH + ((2 * lane) ^ ((lane & 7) << 4))) = 0x3F80;

    const int swz = (c15 & 7) << 4;       // row-swizzle for rows ≡ c15 (mod 8)
    const int sl0 = (h * 16) ^ swz;       // K-slot ki=0 read offset
    const int sl1 = (64 + h * 16) ^ swz;  // K-slot ki=1 read offset

    int eoff[9];  // E-write offsets (step-invariant, swizzled)
#pragma unroll
    for (int i = 0; i < 9; ++i) {
      int flat = i * 256 + lane * 4;
      int r = flat / 48;
      eoff[i] = r * RPITCH + ((2 * (flat - r * 48)) ^ ((r & 7) << 4));
    }

    const int t0 = cix << 4;
    const float* tb = scores + ((size_t)b * T_LEN + t0) * (KK * KK);
    int tgt_l = 0;
    if (lane < 16) tgt_l = targets[b * T_LEN + t0 + lane];

    const float C1 = 1.4426950408889634f;  // log2(e)
    int logE = 0;
    float goldn = 0.0f;

    for (int s = steps - 1; s >= 0; --s) {
      // load this step's 48x48 f32 tile (coalesced, 9 x float4/lane)
      float4 curv[9];
      {
        const float4* gp = (const float4*)(tb + (size_t)s * (KK * KK));
#pragma unroll
        for (int i = 0; i < 9; ++i) curv[i] = gp[i * 64 + lane];
      }
      {  // gold += S_s[target] from in-register tile (exact f32)
        int tg = __shfl(tgt_l, s);
        tg = __builtin_amdgcn_readfirstlane(tg);
        float4 tt;
        switch (tg >> 8) {
          case 0: tt = curv[0]; break; case 1: tt = curv[1]; break;
          case 2: tt = curv[2]; break; case 3: tt = curv[3]; break;
          case 4: tt = curv[4]; break; case 5: tt = curv[5]; break;
          case 6: tt = curv[6]; break; case 7: tt = curv[7]; break;
          default: tt = curv[8]; break;
        }
        int q = tg & 3;
        float cand = (q == 0) ? tt.x : (q == 1) ? tt.y : (q == 2) ? tt.z : tt.w;
        goldn += __shfl(cand, (tg >> 2) & 63);
      }
      // E = exp(S_s) bf16 (cvt_pk), swizzled rows
#pragma unroll
      for (int i = 0; i < 9; ++i) {
        uint2 pk;
        pk.x = cvt_pk_bf16(exp2f(curv[i].x * C1), exp2f(curv[i].y * C1));
        pk.y = cvt_pk_bf16(exp2f(curv[i].z * C1), exp2f(curv[i].w * C1));
        *(uint2*)(E + eoff[i]) = pk;
      }
      // fragments: all ds_read_b128, <=2-way banked (free)
      short8 afr[3][2], bfr[2][3];
#pragma unroll
      for (int mi = 0; mi < 3; ++mi) {
        afr[mi][0] = *(const short8*)(E + (mi * 16 + c15) * RPITCH + sl0);
        afr[mi][1] = *(const short8*)(E + (mi * 16 + c15) * RPITCH + sl1);
      }
#pragma unroll
      for (int ni = 0; ni < 3; ++ni) {
        bfr[0][ni] = *(const short8*)(TM + (ni * 16 + c15) * RPITCH + sl0);
        bfr[1][ni] = *(const short8*)(TM + (ni * 16 + c15) * RPITCH + sl1);
      }
      f32x4 acc[3][3];
#pragma unroll
      for (int mi = 0; mi < 3; ++mi)
#pragma unroll
        for (int ni = 0; ni < 3; ++ni) {
          f32x4 d = {0.f, 0.f, 0.f, 0.f};
          d = __builtin_amdgcn_mfma_f32_16x16x32_bf16(afr[mi][0], bfr[0][ni], d, 0, 0, 0);
          d = __builtin_amdgcn_mfma_f32_16x16x32_bf16(afr[mi][1], bfr[1][ni], d, 0, 0, 0);
          acc[mi][ni] = d;
        }
      // periodic exact renorm (exponent strip)
      int it = (steps - 1) - s;
      if (((it & 3) == 3) || s == 0) {
        float mx = 0.0f;
#pragma unroll
        for (int mi = 0; mi < 3; ++mi)
#pragma unroll
          for (int ni = 0; ni < 3; ++ni)
#pragma unroll
            for (int rr = 0; rr < 4; ++rr) mx = fmaxf(mx, acc[mi][ni][rr]);
#pragma unroll
        for (int d = 1; d < 64; d <<= 1) mx = fmaxf(mx, __shfl_xor(mx, d));
        int ex = (int)((__float_as_uint(mx) >> 23) & 255) - 127;
        float sc = __uint_as_float((uint32_t)(127 - ex) << 23);
        logE += ex;
#pragma unroll
        for (int mi = 0; mi < 3; ++mi)
#pragma unroll
          for (int ni = 0; ni < 3; ++ni)
#pragma unroll
            for (int rr = 0; rr < 4; ++rr) acc[mi][ni][rr] *= sc;
      }
      // D -> TM, 8B stores, full-logical-offset XOR swizzle
#pragma unroll
      for (int ni = 0; ni < 3; ++ni)
#pragma unroll
        for (int mi = 0; mi < 3; ++mi) {
          uint2 pk;
          pk.x = cvt_pk_bf16(acc[mi][ni][0], acc[mi][ni][1]);
          pk.y = cvt_pk_bf16(acc[mi][ni][2], acc[mi][ni][3]);
          *(uint2*)(TM + (ni * 16 + c15) * RPITCH + ((mi * 32 + h * 8) ^ swz)) = pk;
        }
    }

    // store transposed chunk matrix densely (48 rows x 96B) at index g=cix*B+b
    unsigned char* gd = wsT + (size_t)g * CHB;
#pragma unroll
    for (int j = 0; j < 9; ++j) {
      int f8 = (j * 64 + lane) * 8;
      int c = f8 / 96;
      int off = f8 - c * 96;
      *(uint2*)(gd + f8) = *(const uint2*)(TM + c * RPITCH + (off ^ ((c & 7) << 4)));
    }
    if (lane == 0) {
      wsExpo[g] = logE;
      wsGold[g] = goldn;
    }
  }

  // ---- signal completion; 32nd chunk-wave of batch b runs the combine ----
  int old = 0;
  if (lane == 0)
    old = __hip_atomic_fetch_add(&wsCnt[b], 1, __ATOMIC_ACQ_REL,
                                 __HIP_MEMORY_SCOPE_AGENT);
  old = __shfl(old, 0);
  if (old != 31) return;

  // winner wave: serial alpha matvec over nc chunk matrices of batch b
  const int nc = (len + 15) >> 4;
  float* als = (float*)smem[wid];  // this wave's LDS region as alpha scratch
  float a = (lane == NSTART) ? 1.0f : 0.0f;
  int expoSum = 0;
  float goldSum = 0.0f;
  uint4 cur[6] = {}, nxt[6] = {};
  if (lane < KK) {
#pragma unroll
    for (int q = 0; q < 6; ++q)
      cur[q] = *(const uint4*)(wsT + (size_t)b * CHB + lane * 96 + q * 16);
  }
  for (int c = 0; c < nc; ++c) {
    if (c + 1 < nc && lane < KK) {
      const unsigned char* nb = wsT + (size_t)((c + 1) * B + b) * CHB;
#pragma unroll
      for (int q = 0; q < 6; ++q) nxt[q] = *(const uint4*)(nb + lane * 96 + q * 16);
    }
    expoSum += wsExpo[c * B + b];
    goldSum += wsGold[c * B + b];
    als[lane] = a;
    f32x4 A4[12];
#pragma unroll
    for (int q = 0; q < 12; ++q) A4[q] = *(const f32x4*)&als[q * 4];
    float s0 = 0.f, s1 = 0.f, s2 = 0.f, s3 = 0.f;
#pragma unroll
    for (int q = 0; q < 6; ++q) {  // lane j: s_j = sum_i alpha_i * M[i][j]
      uint4 w = cur[q];
      f32x4 a0 = A4[2 * q], a1 = A4[2 * q + 1];
      s0 = fmaf(a0[0], bf2f(w.x & 0xFFFFu), s0);
      s1 = fmaf(a0[1], bf2f(w.x >> 16), s1);
      s2 = fmaf(a0[2], bf2f(w.y & 0xFFFFu), s2);
      s3 = fmaf(a0[3], bf2f(w.y >> 16), s3);
      s0 = fmaf(a1[0], bf2f(w.z & 0xFFFFu), s0);
      s1 = fmaf(a1[1], bf2f(w.z >> 16), s1);
      s2 = fmaf(a1[2], bf2f(w.w & 0xFFFFu), s2);
      s3 = fmaf(a1[3], bf2f(w.w >> 16), s3);
    }
    float s = (s0 + s1) + (s2 + s3);  // lane>=48: cur==0 -> 0
    float mx = s;
#pragma unroll
    for (int d = 1; d < 64; d <<= 1) mx = fmaxf(mx, __shfl_xor(mx, d));
    int ex = (int)((__float_as_uint(mx) >> 23) & 255) - 127;
    a = s * __uint_as_float((uint32_t)(127 - ex) << 23);
    expoSum += ex;
    if (c + 1 < nc) {
#pragma unroll
      for (int q = 0; q < 6; ++q) cur[q] = nxt[q];
    }
  }
  if (lane == NEND)
    out[b] = 0.69314718055994531f * (log2f(a) + (float)expoSum) - goldSum;
}

extern "C" void kernel_launch(void* const* d_in, const int* in_sizes, int n_in,
                              void* d_out, int out_size, void* d_ws,
                              size_t ws_size, hipStream_t stream) {
  const float* scores = (const float*)d_in[0];
  const int* targets = (const int*)d_in[1];
  const void* mask = (const void*)d_in[2];
  float* out = (float*)d_out;
  const int B = in_sizes[1] / T_LEN;
  const int nch = B * 32;

  unsigned char* wsT = (unsigned char*)d_ws;      // nch * 4608
  int* wsExpo = (int*)(wsT + (size_t)nch * CHB);  // nch ints
  float* wsGold = (float*)(wsExpo + nch);         // nch floats
  int* wsCnt = (int*)(wsGold + nch);              // B ints

  hipMemsetAsync(wsCnt, 0, (size_t)B * sizeof(int), stream);
  k2_fused<<<(nch + 3) / 4, 256, 0, stream>>>(scores, targets, mask, wsT,
                                              wsExpo, wsGold, wsCnt, out, nch, B);
}

// Round 9
// 82.184 us; speedup vs baseline: 2.2373x; 2.2373x over previous
//
#include <hip/hip_runtime.h>
#include <stdint.h>

// CRF forward loss, chunked parallel scan in linear space.
// K2: one wave per 16-step chunk (nch = 32*B waves, all resident at 8/CU).
//     M <- E_s * M, s descending. A-operand (E_s = exp(S_s)) is built DIRECTLY
//     in registers from 12 coalesced dwordx4 global loads per step (no E LDS
//     region, no staging). B-operand = M via transposed LDS image TM (6144 B
//     per wave) with XOR-16B swizzle; D written back to TM as 8B stores.
//     Gold = one lane-0 dword load per step (tile is L1-resident).
//     No fused combine (round-7 spill lesson: VGPR 80 + 140 MB scratch).
// K3: per-batch serial alpha matvec over <=32 transposed chunk matrices.

#define T_LEN 512
#define KK 48
#define NSTART 46
#define NEND 47
#define RPITCH 128               // TM row: 64 bf16 (48 real + 16 zero K-pad)
#define WAVE_LDS (48 * RPITCH)   // 6144 B per wave (TM only)
#define CHB 4608                 // 48x48 bf16 chunk matrix (transposed, pitch 96)

typedef __attribute__((ext_vector_type(8))) short short8;
typedef __attribute__((ext_vector_type(4))) float f32x4;

__device__ __forceinline__ uint32_t cvt_pk_bf16(float lo, float hi) {
  uint32_t r;
  asm("v_cvt_pk_bf16_f32 %0, %1, %2" : "=v"(r) : "v"(lo), "v"(hi));
  return r;  // lo in bits 0..15, hi in bits 16..31 (RNE)
}
__device__ __forceinline__ float bf2f(uint32_t h) { return __uint_as_float(h << 16); }

// decode mask encoding (u8 bool / f32 / i32 / i64), popcount row b (prefix mask)
__device__ __forceinline__ int mask_len(const void* mask, int b, int lane) {
  const uint32_t w0 = ((const uint32_t*)mask)[0];
  const uint32_t w1 = ((const uint32_t*)mask)[1];
  int c = 0;
  if (w0 == 0x01010101u) {
    const unsigned long long* m8 =
        (const unsigned long long*)((const unsigned char*)mask + (size_t)b * T_LEN);
    c = (int)__popcll(m8[lane]);
  } else if (w0 == 0x3F800000u) {
    const float* mf = (const float*)mask + (size_t)b * T_LEN;
#pragma unroll
    for (int j = 0; j < 8; ++j) c += (mf[lane + 64 * j] != 0.0f);
  } else if (w1 == 1u) {
    const uint32_t* mi = (const uint32_t*)mask + (size_t)b * T_LEN;
#pragma unroll
    for (int j = 0; j < 8; ++j) c += (mi[lane + 64 * j] != 0u);
  } else {
    const unsigned long long* ml =
        (const unsigned long long*)mask + (size_t)b * T_LEN;
#pragma unroll
    for (int j = 0; j < 8; ++j) c += (ml[lane + 64 * j] != 0ull);
  }
#pragma unroll
  for (int d = 1; d < 64; d <<= 1) c += __shfl_xor(c, d);
  return c > T_LEN ? T_LEN : (c < 0 ? 0 : c);
}

// ---------------- K2: chunk products ----------------
__global__ __launch_bounds__(256, 2) void k2_chunks(
    const float* __restrict__ scores, const int* __restrict__ targets,
    const void* __restrict__ mask, unsigned char* __restrict__ wsT,
    int* __restrict__ wsExpo, float* __restrict__ wsGold, int nch, int B) {
  __shared__ __align__(16) unsigned char smem[4][WAVE_LDS];
  const int wid = threadIdx.x >> 6, lane = threadIdx.x & 63;
  const int g = blockIdx.x * 4 + wid;
  if (g >= nch) return;
  const int cix = g / B;  // balanced: consecutive g -> same cix, diff b
  const int b = g - cix * B;
  const int len = mask_len(mask, b, lane);
  int steps = len - (cix << 4);
  if (steps <= 0) return;  // never consumed by K3
  if (steps > 16) steps = 16;

  unsigned char* TM = smem[wid];  // M transposed; K-pad bytes 96..127 stay 0

  {  // zero TM: 384 x 16B
    int4* z = (int4*)TM;
#pragma unroll
    for (int q = 0; q < 6; ++q) z[q * 64 + lane] = make_int4(0, 0, 0, 0);
  }
  // M := I (swizzled address: full logical offset XOR row-swizzle)
  if (lane < KK)
    *(ushort*)(TM + lane * RPITCH + ((2 * lane) ^ ((lane & 7) << 4))) = 0x3F80;

  const int c15 = lane & 15, h = lane >> 4;
  const int swz = (c15 & 7) << 4;       // row-swizzle for rows ≡ c15 (mod 8)
  const int sl0 = (h * 16) ^ swz;       // K-slot ki=0 read offset
  const int sl1 = (64 + h * 16) ^ swz;  // K-slot ki=1 read offset
  const int hm = (h < 2) ? h : 1;       // ki=1 col clamp (k>=48 is pad)
  const uint32_t kmask1 = (h < 2) ? 0xFFFFFFFFu : 0u;  // zero pad A-frags

  // per-mi, per-lane byte offsets of this lane's A-fragment within a tile:
  // A[m][k]: m = mi*16 + c15 (row, 192 B), k = ki*32 + 8h + j (f32 col)
  int aoff0[3], aoff1[3];
#pragma unroll
  for (int mi = 0; mi < 3; ++mi) {
    int rowb = (mi * 16 + c15) * 192;
    aoff0[mi] = rowb + h * 32;          // ki=0: cols 8h..8h+7 (2 x 16B)
    aoff1[mi] = rowb + 128 + hm * 32;   // ki=1: cols 32+8hm.. (clamped, masked)
  }

  const int t0 = cix << 4;
  const unsigned char* tb =
      (const unsigned char*)(scores + ((size_t)b * T_LEN + t0) * (KK * KK));
  int tgt_l = 0;
  if (lane < 16) tgt_l = targets[b * T_LEN + t0 + lane];

  const float C1 = 1.4426950408889634f;  // log2(e)
  int logE = 0;
  float goldn = 0.0f;

  for (int s = steps - 1; s >= 0; --s) {
    const unsigned char* tbase = tb + (size_t)s * 9216;
    // 12 coalesced dwordx4: the wave covers the 9216B tile exactly once
    float4 a0[3], a1[3], a2[3], a3[3];
#pragma unroll
    for (int mi = 0; mi < 3; ++mi) {
      a0[mi] = *(const float4*)(tbase + aoff0[mi]);
      a1[mi] = *(const float4*)(tbase + aoff0[mi] + 16);
      a2[mi] = *(const float4*)(tbase + aoff1[mi]);
      a3[mi] = *(const float4*)(tbase + aoff1[mi] + 16);
    }
    {  // gold += S_s[target]; tile bytes are L1-resident from the loads above
      int tg = __shfl(tgt_l, s);
      if (lane == 0) goldn += *(const float*)(tbase + 4 * (size_t)tg);
    }
    // A-frags: exp2 + pack in-register (bit-identical to LDS-staged path)
    short8 afr[3][2];
#pragma unroll
    for (int mi = 0; mi < 3; ++mi) {
      union { short8 s8; uint32_t u[4]; } u0, u1;
      u0.u[0] = cvt_pk_bf16(exp2f(a0[mi].x * C1), exp2f(a0[mi].y * C1));
      u0.u[1] = cvt_pk_bf16(exp2f(a0[mi].z * C1), exp2f(a0[mi].w * C1));
      u0.u[2] = cvt_pk_bf16(exp2f(a1[mi].x * C1), exp2f(a1[mi].y * C1));
      u0.u[3] = cvt_pk_bf16(exp2f(a1[mi].z * C1), exp2f(a1[mi].w * C1));
      u1.u[0] = cvt_pk_bf16(exp2f(a2[mi].x * C1), exp2f(a2[mi].y * C1)) & kmask1;
      u1.u[1] = cvt_pk_bf16(exp2f(a2[mi].z * C1), exp2f(a2[mi].w * C1)) & kmask1;
      u1.u[2] = cvt_pk_bf16(exp2f(a3[mi].x * C1), exp2f(a3[mi].y * C1)) & kmask1;
      u1.u[3] = cvt_pk_bf16(exp2f(a3[mi].z * C1), exp2f(a3[mi].w * C1)) & kmask1;
      afr[mi][0] = u0.s8;
      afr[mi][1] = u1.s8;
    }
    // B-frags from TM: 6 x ds_read_b128, <=2-way banked (free)
    short8 bfr[2][3];
#pragma unroll
    for (int ni = 0; ni < 3; ++ni) {
      bfr[0][ni] = *(const short8*)(TM + (ni * 16 + c15) * RPITCH + sl0);
      bfr[1][ni] = *(const short8*)(TM + (ni * 16 + c15) * RPITCH + sl1);
    }
    f32x4 acc[3][3];
#pragma unroll
    for (int mi = 0; mi < 3; ++mi)
#pragma unroll
      for (int ni = 0; ni < 3; ++ni) {
        f32x4 d = {0.f, 0.f, 0.f, 0.f};
        d = __builtin_amdgcn_mfma_f32_16x16x32_bf16(afr[mi][0], bfr[0][ni], d, 0, 0, 0);
        d = __builtin_amdgcn_mfma_f32_16x16x32_bf16(afr[mi][1], bfr[1][ni], d, 0, 0, 0);
        acc[mi][ni] = d;
      }
    // periodic exact renorm (exponent strip)
    int it = (steps - 1) - s;
    if (((it & 3) == 3) || s == 0) {
      float mx = 0.0f;
#pragma unroll
      for (int mi = 0; mi < 3; ++mi)
#pragma unroll
        for (int ni = 0; ni < 3; ++ni)
#pragma unroll
          for (int rr = 0; rr < 4; ++rr) mx = fmaxf(mx, acc[mi][ni][rr]);
#pragma unroll
      for (int d = 1; d < 64; d <<= 1) mx = fmaxf(mx, __shfl_xor(mx, d));
      int ex = (int)((__float_as_uint(mx) >> 23) & 255) - 127;
      float sc = __uint_as_float((uint32_t)(127 - ex) << 23);
      logE += ex;
#pragma unroll
      for (int mi = 0; mi < 3; ++mi)
#pragma unroll
        for (int ni = 0; ni < 3; ++ni)
#pragma unroll
          for (int rr = 0; rr < 4; ++rr) acc[mi][ni][rr] *= sc;
    }
    // D -> TM, 8B stores, full-logical-offset XOR swizzle
#pragma unroll
    for (int ni = 0; ni < 3; ++ni)
#pragma unroll
      for (int mi = 0; mi < 3; ++mi) {
        uint2 pk;
        pk.x = cvt_pk_bf16(acc[mi][ni][0], acc[mi][ni][1]);
        pk.y = cvt_pk_bf16(acc[mi][ni][2], acc[mi][ni][3]);
        *(uint2*)(TM + (ni * 16 + c15) * RPITCH + ((mi * 32 + h * 8) ^ swz)) = pk;
      }
  }

  // store transposed chunk matrix densely (48 rows x 96B) at index g=cix*B+b
  unsigned char* gd = wsT + (size_t)g * CHB;
#pragma unroll
  for (int j = 0; j < 9; ++j) {
    int f8 = (j * 64 + lane) * 8;
    int c = f8 / 96;
    int off = f8 - c * 96;
    *(uint2*)(gd + f8) = *(const uint2*)(TM + c * RPITCH + (off ^ ((c & 7) << 4)));
  }
  if (lane == 0) {
    wsExpo[g] = logE;
    wsGold[g] = goldn;  // goldn valid on lane 0
  }
}

// ---------------- K3: per-batch combine ----------------
__global__ __launch_bounds__(64) void k3_combine(
    const unsigned char* __restrict__ wsT, const int* __restrict__ wsExpo,
    const float* __restrict__ wsGold, const void* __restrict__ mask,
    float* __restrict__ out, int B) {
  __shared__ float alpha_s[64];
  const int b = blockIdx.x, lane = threadIdx.x & 63;
  const int len = mask_len(mask, b, lane);
  const int nc = (len + 15) >> 4;

  float a = (lane == NSTART) ? 1.0f : 0.0f;
  int expoSum = 0;
  float goldSum = 0.0f;
  uint4 cur[6] = {}, nxt[6] = {};
  if (lane < KK) {
#pragma unroll
    for (int q = 0; q < 6; ++q)
      cur[q] = *(const uint4*)(wsT + (size_t)b * CHB + lane * 96 + q * 16);
  }
  for (int c = 0; c < nc; ++c) {
    if (c + 1 < nc && lane < KK) {
      const unsigned char* nb = wsT + (size_t)((c + 1) * B + b) * CHB;
#pragma unroll
      for (int q = 0; q < 6; ++q) nxt[q] = *(const uint4*)(nb + lane * 96 + q * 16);
    }
    expoSum += wsExpo[c * B + b];
    goldSum += wsGold[c * B + b];
    alpha_s[lane] = a;
    f32x4 A4[12];
#pragma unroll
    for (int q = 0; q < 12; ++q) A4[q] = *(const f32x4*)&alpha_s[q * 4];
    float s0 = 0.f, s1 = 0.f, s2 = 0.f, s3 = 0.f;
#pragma unroll
    for (int q = 0; q < 6; ++q) {  // lane j: s_j = sum_i alpha_i * M[i][j]
      uint4 w = cur[q];
      f32x4 a0 = A4[2 * q], a1 = A4[2 * q + 1];
      s0 = fmaf(a0[0], bf2f(w.x & 0xFFFFu), s0);
      s1 = fmaf(a0[1], bf2f(w.x >> 16), s1);
      s2 = fmaf(a0[2], bf2f(w.y & 0xFFFFu), s2);
      s3 = fmaf(a0[3], bf2f(w.y >> 16), s3);
      s0 = fmaf(a1[0], bf2f(w.z & 0xFFFFu), s0);
      s1 = fmaf(a1[1], bf2f(w.z >> 16), s1);
      s2 = fmaf(a1[2], bf2f(w.w & 0xFFFFu), s2);
      s3 = fmaf(a1[3], bf2f(w.w >> 16), s3);
    }
    float s = (s0 + s1) + (s2 + s3);  // lane>=48: cur==0 -> 0
    float mx = s;
#pragma unroll
    for (int d = 1; d < 64; d <<= 1) mx = fmaxf(mx, __shfl_xor(mx, d));
    int ex = (int)((__float_as_uint(mx) >> 23) & 255) - 127;
    a = s * __uint_as_float((uint32_t)(127 - ex) << 23);
    expoSum += ex;
    if (c + 1 < nc) {
#pragma unroll
      for (int q = 0; q < 6; ++q) cur[q] = nxt[q];
    }
  }
  if (lane == NEND)
    out[b] = 0.69314718055994531f * (log2f(a) + (float)expoSum) - goldSum;
}

extern "C" void kernel_launch(void* const* d_in, const int* in_sizes, int n_in,
                              void* d_out, int out_size, void* d_ws,
                              size_t ws_size, hipStream_t stream) {
  const float* scores = (const float*)d_in[0];
  const int* targets = (const int*)d_in[1];
  const void* mask = (const void*)d_in[2];
  float* out = (float*)d_out;
  const int B = in_sizes[1] / T_LEN;
  const int nch = B * 32;

  unsigned char* wsT = (unsigned char*)d_ws;      // nch * 4608
  int* wsExpo = (int*)(wsT + (size_t)nch * CHB);  // nch ints
  float* wsGold = (float*)(wsExpo + nch);         // nch floats

  k2_chunks<<<(nch + 3) / 4, 256, 0, stream>>>(scores, targets, mask, wsT,
                                               wsExpo, wsGold, nch, B);
  k3_combine<<<B, 64, 0, stream>>>(wsT, wsExpo, wsGold, mask, out, B);
}